// Round 8
// baseline (347.467 us; speedup 1.0000x reference)
//
#include <hip/hip_runtime.h>
#include <math.h>

#define NN      262144
#define WC      128
#define RR      4
#define OUTD    512
#define IFACED  919
#define CD      1431
#define C4      5724
#define VROWS   1559   // CD + WC virtual rows ([h ; xt])
#define PROJ_J  1157   // 512 out + 645 used iface entries
#define CMAX    2048   // candidate cap (E[n]=524 @ thr 2e-3)

// zmv 2D grid: 90 col-tiles(64) x 5 row-chunks(312) = 450 blocks
#define ZCT     90
#define ZKC     5
#define ZROWS   312    // 8 waves x 39 rows
#define ZGRID   450
// proj 2D grid: 19 col-tiles(64) x 8 row-chunks(179) = 152 blocks
#define PCT     19
#define PKC     8
#define PROWS   179    // 8 waves x 23 rows (clamped)
#define PGRID   152

// ---- ws word offsets (everything fully re-written each iteration; no init)
#define OFF_CA      0        // f32[1431] c ping
#define OFF_CB      1536     // f32[1431] c pong
#define OFF_ZP      3072     // f32[5 steps][5 kc][C4] = 143100
#define OFF_PP      146176   // f32[8][PROJ_J] = 9256
#define OFF_BSUM    155456   // f32[512*5]
#define OFF_CCNT    158016   // u32 (own line)
#define OFF_CAND    158080   // u64[2048] (even word -> 8B aligned)
#define OFF_SCORES  162176   // f32[5*NN]

__device__ __forceinline__ float sigm(float x) { return 1.f / (1.f + expf(-x)); }
__device__ __forceinline__ float softplusf(float x) { return x > 20.f ? x : log1pf(expf(x)); }

// ---- gates for rows [r0, r1c): z = lb + sum of 5 zpart chunks; h -> sv -----
__device__ __forceinline__ void do_gates_part(const float* __restrict__ zp,
    const float* __restrict__ lb, const float* __restrict__ cprev,
    float* __restrict__ cnext, float* sv, int r0, int r1c, bool writeC) {
  for (int j = r0 + (int)threadIdx.x; j < r1c; j += 512) {
    float zi = lb[j], zf = lb[CD + j], zg = lb[2 * CD + j], zo = lb[3 * CD + j];
    #pragma unroll
    for (int kc = 0; kc < ZKC; ++kc) {
      const float* zz = zp + (size_t)kc * C4;
      zi += zz[j]; zf += zz[CD + j]; zg += zz[2 * CD + j]; zo += zz[3 * CD + j];
    }
    float cn = sigm(zf) * cprev[j] + sigm(zi) * tanhf(zg);
    if (writeC) cnext[j] = cn;
    sv[j] = sigm(zo) * tanhf(cn);
  }
  __syncthreads();
}

// ---- zmv partial: block (ct,kc) computes rows[kc] x cols[ct] -> zpart.
// Inner loop batch-8: 8 independent row loads in flight per exposure (the
// round-7 version chained ~4 deep -> latency-bound at ~900cy L3/HBM lat).
__device__ __forceinline__ void do_zmv(const float* __restrict__ lr,
    const float* __restrict__ lk, const float* sv, float* __restrict__ zout,
    float* zred) {
  const int wave = threadIdx.x >> 6, lane = threadIdx.x & 63;
  const int ct = blockIdx.x % ZCT, kc = blockIdx.x / ZCT;
  const int j0 = ct * 64;
  int ncol = C4 - j0; if (ncol > 64) ncol = 64;
  int rw0 = kc * ZROWS + wave * 39, rw1 = rw0 + 39;
  if (rw1 > VROWS) rw1 = VROWS;
  float a0 = 0, a1 = 0, a2 = 0, a3 = 0, a4 = 0, a5 = 0, a6 = 0, a7 = 0;
  if (lane < ncol && rw0 < rw1) {
    int rb = rw1 < CD ? rw1 : CD;
    int k = rw0;
    if (k < rb) {
      const float* p = lr + (size_t)k * C4 + (j0 + lane);
      for (; k + 8 <= rb; k += 8) {
        float w0 = p[0],                w1 = p[(size_t)C4];
        float w2 = p[2 * (size_t)C4],   w3 = p[3 * (size_t)C4];
        float w4 = p[4 * (size_t)C4],   w5 = p[5 * (size_t)C4];
        float w6 = p[6 * (size_t)C4],   w7 = p[7 * (size_t)C4];
        a0 = fmaf(sv[k],     w0, a0); a1 = fmaf(sv[k + 1], w1, a1);
        a2 = fmaf(sv[k + 2], w2, a2); a3 = fmaf(sv[k + 3], w3, a3);
        a4 = fmaf(sv[k + 4], w4, a4); a5 = fmaf(sv[k + 5], w5, a5);
        a6 = fmaf(sv[k + 6], w6, a6); a7 = fmaf(sv[k + 7], w7, a7);
        p += 8 * (size_t)C4;
      }
      for (; k < rb; ++k) { a0 = fmaf(sv[k], *p, a0); p += C4; }
    }
    if (rw1 > CD) {                       // xt rows (only kc==4 blocks)
      int ka = rw0 > CD ? rw0 : CD;
      const float* q = lk + (size_t)(ka - CD) * C4 + (j0 + lane);
      int k2 = ka;
      for (; k2 + 8 <= rw1; k2 += 8) {
        float w0 = q[0],                w1 = q[(size_t)C4];
        float w2 = q[2 * (size_t)C4],   w3 = q[3 * (size_t)C4];
        float w4 = q[4 * (size_t)C4],   w5 = q[5 * (size_t)C4];
        float w6 = q[6 * (size_t)C4],   w7 = q[7 * (size_t)C4];
        a0 = fmaf(sv[k2],     w0, a0); a1 = fmaf(sv[k2 + 1], w1, a1);
        a2 = fmaf(sv[k2 + 2], w2, a2); a3 = fmaf(sv[k2 + 3], w3, a3);
        a4 = fmaf(sv[k2 + 4], w4, a4); a5 = fmaf(sv[k2 + 5], w5, a5);
        a6 = fmaf(sv[k2 + 6], w6, a6); a7 = fmaf(sv[k2 + 7], w7, a7);
        q += 8 * (size_t)C4;
      }
      for (; k2 < rw1; ++k2) { a0 = fmaf(sv[k2], *q, a0); q += C4; }
    }
  }
  zred[threadIdx.x] = ((a0 + a1) + (a2 + a3)) + ((a4 + a5) + (a6 + a7));
  __syncthreads();
  if ((int)threadIdx.x < ncol) {
    float s = zred[threadIdx.x]       + zred[threadIdx.x + 64] +
              zred[threadIdx.x + 128] + zred[threadIdx.x + 192] +
              zred[threadIdx.x + 256] + zred[threadIdx.x + 320] +
              zred[threadIdx.x + 384] + zred[threadIdx.x + 448];
    zout[(size_t)kc * C4 + j0 + threadIdx.x] = s;
  }
}

// ---- k1: z1 partials from [h0 ; xw]. xw computed ONLY by kc==4 blocks
// (the only chunk containing xt rows) — round 7 had all 450 blocks pull
// dk (256KB x 450 = 115MB of L2/L3 traffic) redundantly.
__global__ __launch_bounds__(512) void k_z1(const float* __restrict__ x,
    const float* __restrict__ dk, const float* __restrict__ db,
    const float* __restrict__ lk, const float* __restrict__ lr,
    const float* __restrict__ h0, float* __restrict__ ws) {
  __shared__ float sv[VROWS];
  __shared__ float sxw[512];
  __shared__ float zred[512];
  const int kc = blockIdx.x / ZCT;
  for (int t = threadIdx.x; t < CD; t += 512) sv[t] = h0[t];
  if (kc == 4) {
    int j = threadIdx.x & (WC - 1), kcw = threadIdx.x >> 7;
    const float* col = dk + j;
    float a = 0.f;
    int k0 = kcw * 128;
    #pragma unroll 8
    for (int k = k0; k < k0 + 128; ++k) a = fmaf(x[k], col[(size_t)k * WC], a);
    sxw[threadIdx.x] = a;
  }
  __syncthreads();
  if (kc == 4 && threadIdx.x < WC)
    sv[CD + threadIdx.x] = db[threadIdx.x] + sxw[threadIdx.x] +
        sxw[threadIdx.x + 128] + sxw[threadIdx.x + 256] + sxw[threadIdx.x + 384];
  __syncthreads();
  do_zmv(lr, lk, sv, ws + OFF_ZP, zred);
}

// ---- k2..k5: gates(t) on own row-chunk + zmv(t+1) -------------------------
__global__ __launch_bounds__(512) void k_mid(const float* __restrict__ lk,
    const float* __restrict__ lr, const float* __restrict__ lb,
    const float* __restrict__ zp_in, const float* __restrict__ cprev,
    float* __restrict__ cnext, const float* __restrict__ xt,
    float* __restrict__ zp_out) {
  __shared__ float sv[VROWS];
  __shared__ float zred[512];
  const int ct = blockIdx.x % ZCT, kc = blockIdx.x / ZCT;
  int r0 = kc * ZROWS, r1 = r0 + ZROWS; if (r1 > VROWS) r1 = VROWS;
  int r1c = r1 < CD ? r1 : CD;
  // ct==0 block of each kc writes c for its (disjoint) row range
  do_gates_part(zp_in, lb, cprev, cnext, sv, r0, r1c, ct == 0);
  if (kc == 4 && threadIdx.x < WC) sv[CD + threadIdx.x] = xt[threadIdx.x];
  __syncthreads();
  do_zmv(lr, lk, sv, zp_out, zred);
}

// ---- k6: gates(5) on own row-chunk + proj partials (batch-8 loads) --------
__global__ __launch_bounds__(512) void k_last(const float* __restrict__ lb,
    const float* __restrict__ zp_in, const float* __restrict__ cprev,
    const float* __restrict__ Wo, const float* __restrict__ Wi,
    float* __restrict__ ws) {
  __shared__ float sv[VROWS];
  __shared__ float zred[512];
  const int wave = threadIdx.x >> 6, lane = threadIdx.x & 63;
  const int ct = blockIdx.x % PCT, kc = blockIdx.x / PCT;
  int r0 = kc * PROWS, r1 = r0 + PROWS; if (r1 > CD) r1 = CD;
  do_gates_part(zp_in, lb, cprev, nullptr, sv, r0, r1, false);
  if (blockIdx.x == 0 && threadIdx.x == 0) *(unsigned*)(ws + OFF_CCNT) = 0u;
  const int j0 = ct * 64;
  int ncol = PROJ_J - j0; if (ncol > 64) ncol = 64;
  int rw0 = r0 + wave * 23, rw1 = rw0 + 23; if (rw1 > r1) rw1 = r1;
  float a0 = 0, a1 = 0, a2 = 0, a3 = 0, a4 = 0, a5 = 0, a6 = 0, a7 = 0;
  if (lane < ncol && rw0 < rw1) {
    const float* p; size_t st;
    if (j0 < OUTD) { p = Wo + (size_t)rw0 * OUTD + (j0 + lane); st = OUTD; }
    else { p = Wi + (size_t)rw0 * IFACED + (j0 - OUTD + lane); st = IFACED; }
    int k = rw0;
    for (; k + 8 <= rw1; k += 8) {
      float w0 = p[0],      w1 = p[st],     w2 = p[2 * st], w3 = p[3 * st];
      float w4 = p[4 * st], w5 = p[5 * st], w6 = p[6 * st], w7 = p[7 * st];
      a0 = fmaf(sv[k],     w0, a0); a1 = fmaf(sv[k + 1], w1, a1);
      a2 = fmaf(sv[k + 2], w2, a2); a3 = fmaf(sv[k + 3], w3, a3);
      a4 = fmaf(sv[k + 4], w4, a4); a5 = fmaf(sv[k + 5], w5, a5);
      a6 = fmaf(sv[k + 6], w6, a6); a7 = fmaf(sv[k + 7], w7, a7);
      p += 8 * st;
    }
    for (; k < rw1; ++k) { a0 = fmaf(sv[k], *p, a0); p += st; }
  }
  zred[threadIdx.x] = ((a0 + a1) + (a2 + a3)) + ((a4 + a5) + (a6 + a7));
  __syncthreads();
  if ((int)threadIdx.x < ncol) {
    float s = zred[threadIdx.x]       + zred[threadIdx.x + 64] +
              zred[threadIdx.x + 128] + zred[threadIdx.x + 192] +
              zred[threadIdx.x + 256] + zred[threadIdx.x + 320] +
              zred[threadIdx.x + 384] + zred[threadIdx.x + 448];
    ws[OFF_PP + (size_t)kc * PROJ_J + j0 + threadIdx.x] = s;
  }
}

// ---- k7: reduce ppart -> keys (redundant) ; scores 1 row/thread -----------
__global__ __launch_bounds__(512) void k_scores(const float* __restrict__ M,
    const float* __restrict__ us, float* __restrict__ out, float* __restrict__ ws) {
  __shared__ float sifc[IFACED];
  __shared__ float s_rk[RR * WC];
  __shared__ float s_wk[WC];
  __shared__ float swred[8][5];
  const float* pp = ws + OFF_PP;
  for (int c = threadIdx.x; c < IFACED; c += 512) {
    float s = 0.f;
    #pragma unroll
    for (int kc = 0; kc < PKC; ++kc) s += pp[(size_t)kc * PROJ_J + OUTD + c];
    sifc[c] = s;
  }
  if (blockIdx.x == 0) {           // out-proj final reduce
    float s = 0.f;
    #pragma unroll
    for (int kc = 0; kc < PKC; ++kc) s += pp[(size_t)kc * PROJ_J + threadIdx.x];
    out[threadIdx.x] = s;
  }
  __syncthreads();
  if (threadIdx.x < 320) {
    int w = threadIdx.x >> 6, ln = threadIdx.x & 63;
    float beta = 1.f + softplusf((w < 4) ? sifc[RR * WC + w] : sifc[RR * WC + RR + WC]);
    const float* src = (w < 4) ? (sifc + w * WC) : (sifc + RR * WC + RR);
    float v0 = src[ln], v1 = src[ln + 64];
    float sq = v0 * v0 + v1 * v1;
    for (int off = 1; off < 64; off <<= 1) sq += __shfl_xor(sq, off);
    float rn = rsqrtf(fmaxf(sq, 1e-12f)) * beta;
    float* dstp = (w < 4) ? (s_rk + w * WC) : s_wk;
    dstp[ln] = v0 * rn; dstp[ln + 64] = v1 * rn;
  }
  __syncthreads();

  float* scores = ws + OFF_SCORES;
  unsigned* ccnt = (unsigned*)(ws + OFF_CCNT);
  unsigned long long* cand = (unsigned long long*)(ws + OFF_CAND);
  unsigned i = blockIdx.x * 512 + threadIdx.x;   // 512x512 == NN exactly
  const float4* rowp = (const float4*)(M + (size_t)i * WC);
  const float4* K0 = (const float4*)(s_rk);
  const float4* K1 = (const float4*)(s_rk + WC);
  const float4* K2 = (const float4*)(s_rk + 2 * WC);
  const float4* K3 = (const float4*)(s_rk + 3 * WC);
  const float4* KW = (const float4*)(s_wk);
  float a0 = 0, a1 = 0, a2 = 0, a3 = 0, a4 = 0, sq = 0;
  #pragma unroll 4
  for (int k = 0; k < 32; ++k) {
    float4 m = rowp[k];
    float4 c0v = K0[k], c1v = K1[k], c2v = K2[k], c3v = K3[k], cwv = KW[k];
    sq = fmaf(m.x, m.x, fmaf(m.y, m.y, fmaf(m.z, m.z, fmaf(m.w, m.w, sq))));
    a0 = fmaf(m.x, c0v.x, fmaf(m.y, c0v.y, fmaf(m.z, c0v.z, fmaf(m.w, c0v.w, a0))));
    a1 = fmaf(m.x, c1v.x, fmaf(m.y, c1v.y, fmaf(m.z, c1v.z, fmaf(m.w, c1v.w, a1))));
    a2 = fmaf(m.x, c2v.x, fmaf(m.y, c2v.y, fmaf(m.z, c2v.z, fmaf(m.w, c2v.w, a2))));
    a3 = fmaf(m.x, c3v.x, fmaf(m.y, c3v.y, fmaf(m.z, c3v.z, fmaf(m.w, c3v.w, a3))));
    a4 = fmaf(m.x, cwv.x, fmaf(m.y, cwv.y, fmaf(m.z, cwv.z, fmaf(m.w, cwv.w, a4))));
  }
  float rn = rsqrtf(fmaxf(sq, 1e-12f));
  float e0 = expf(a0 * rn), e1 = expf(a1 * rn), e2 = expf(a2 * rn),
        e3 = expf(a3 * rn), e4 = expf(a4 * rn);
  scores[0 * (size_t)NN + i] = e0;
  scores[1 * (size_t)NN + i] = e1;
  scores[2 * (size_t)NN + i] = e2;
  scores[3 * (size_t)NN + i] = e3;
  scores[4 * (size_t)NN + i] = e4;
  out[OUTD + 5 * (size_t)NN + i] = 0.f;          // alloc col zero-fill
  float u = us[i];
  if (u < 2e-3f) {
    unsigned slot = atomicAdd(ccnt, 1u);
    if (slot < CMAX)
      cand[slot] = ((unsigned long long)__float_as_uint(u) << 32) | i;
  }
  float p0 = e0, p1 = e1, p2 = e2, p3 = e3, p4 = e4;
  for (int off = 1; off < 64; off <<= 1) {
    p0 += __shfl_xor(p0, off); p1 += __shfl_xor(p1, off); p2 += __shfl_xor(p2, off);
    p3 += __shfl_xor(p3, off); p4 += __shfl_xor(p4, off);
  }
  int wave = threadIdx.x >> 6, ln = threadIdx.x & 63;
  if (ln == 0) { swred[wave][0] = p0; swred[wave][1] = p1; swred[wave][2] = p2;
                 swred[wave][3] = p3; swred[wave][4] = p4; }
  __syncthreads();
  if (threadIdx.x < 5) {
    float s = 0.f;
    for (int q = 0; q < 8; ++q) s += swred[q][threadIdx.x];
    ws[OFF_BSUM + blockIdx.x * 5 + threadIdx.x] = s;
  }
}

// ---- k8: block 0 alloc ; blocks 1..511 normalize --------------------------
__global__ __launch_bounds__(512) void k_tail(float* __restrict__ out,
    float* __restrict__ ws) {
  __shared__ float swred[8][5];
  __shared__ float ssum[5];
  __shared__ unsigned long long sc[CMAX];
  __shared__ unsigned long long srt[CMAX];
  __shared__ float cpe[200];
  const float* scores = ws + OFF_SCORES;
  if (blockIdx.x == 0) {
    // exact rank-sort of candidates + fp32 cumprod (reference order).
    // cumprod of sorted ascending uniforms underflows after ~10 terms; ranks
    // >=200 keep the zero written by k_scores (ref values there < 1e-38).
    int n = (int)*(const unsigned*)(ws + OFF_CCNT); if (n > CMAX) n = CMAX;
    const unsigned long long* cand = (const unsigned long long*)(ws + OFF_CAND);
    for (int t = threadIdx.x; t < n; t += 512) sc[t] = cand[t];
    __syncthreads();
    for (int t = threadIdx.x; t < n; t += 512) {
      unsigned long long v = sc[t];
      int r = 0;
      for (int j2 = 0; j2 < n; ++j2) r += (sc[j2] < v);
      srt[r] = v;
    }
    __syncthreads();
    int lim = n < 200 ? n : 200;
    if (threadIdx.x == 0) {
      float cp = 1.f;
      for (int r = 0; r < lim; ++r) {
        cpe[r] = cp;
        cp *= __uint_as_float((unsigned)(srt[r] >> 32));
      }
    }
    __syncthreads();
    for (int r = threadIdx.x; r < lim; r += 512) {
      unsigned long long pr = srt[r];
      float s = __uint_as_float((unsigned)(pr >> 32));
      out[OUTD + 5 * (size_t)NN + (unsigned)pr] = (1.f - s) * cpe[r];
    }
  } else {
    const float* bsum = ws + OFF_BSUM;
    float q0 = 0, q1 = 0, q2 = 0, q3 = 0, q4 = 0;
    {
      const float* bp = bsum + threadIdx.x * 5;   // 512 entries, 1 per thread
      q0 = bp[0]; q1 = bp[1]; q2 = bp[2]; q3 = bp[3]; q4 = bp[4];
    }
    for (int off = 1; off < 64; off <<= 1) {
      q0 += __shfl_xor(q0, off); q1 += __shfl_xor(q1, off); q2 += __shfl_xor(q2, off);
      q3 += __shfl_xor(q3, off); q4 += __shfl_xor(q4, off);
    }
    int wave = threadIdx.x >> 6, ln = threadIdx.x & 63;
    if (ln == 0) { swred[wave][0] = q0; swred[wave][1] = q1; swred[wave][2] = q2;
                   swred[wave][3] = q3; swred[wave][4] = q4; }
    __syncthreads();
    if (threadIdx.x < 5) {
      float s = 0.f;
      for (int q = 0; q < 8; ++q) s += swred[q][threadIdx.x];
      ssum[threadIdx.x] = s;
    }
    __syncthreads();
    float i0 = 1.f / ssum[0], i1 = 1.f / ssum[1], i2 = 1.f / ssum[2],
          i3 = 1.f / ssum[3], i4 = 1.f / ssum[4];
    unsigned stride = 511u * 512u;
    for (unsigned i = (blockIdx.x - 1) * 512 + threadIdx.x; i < NN; i += stride) {
      float4 wr;
      wr.x = scores[0 * (size_t)NN + i] * i0;
      wr.y = scores[1 * (size_t)NN + i] * i1;
      wr.z = scores[2 * (size_t)NN + i] * i2;
      wr.w = scores[3 * (size_t)NN + i] * i3;
      *(float4*)(out + OUTD + (size_t)i * 4) = wr;
      out[OUTD + 4 * (size_t)NN + i] = scores[4 * (size_t)NN + i] * i4;
    }
  }
}

extern "C" void kernel_launch(void* const* d_in, const int* in_sizes, int n_in,
                              void* d_out, int out_size, void* d_ws, size_t ws_size,
                              hipStream_t stream) {
  const float* x  = (const float*)d_in[0];
  const float* dk = (const float*)d_in[1];
  const float* db = (const float*)d_in[2];
  const float* lk = (const float*)d_in[3];
  const float* lr = (const float*)d_in[4];
  const float* lb = (const float*)d_in[5];
  const float* h0 = (const float*)d_in[6];
  const float* c0 = (const float*)d_in[7];
  const float* rv = (const float*)d_in[8];
  const float* Wo = (const float*)d_in[9];
  const float* Wi = (const float*)d_in[10];
  const float* M  = (const float*)d_in[11];
  const float* us = (const float*)d_in[12];
  float* out = (float*)d_out;
  float* ws  = (float*)d_ws;

  float* cA = ws + OFF_CA;
  float* cB = ws + OFF_CB;
  #define ZB(s) (ws + OFF_ZP + (size_t)((s) - 1) * ZKC * C4)

  k_z1<<<ZGRID, 512, 0, stream>>>(x, dk, db, lk, lr, h0, ws);
  k_mid<<<ZGRID, 512, 0, stream>>>(lk, lr, lb, ZB(1), c0, cA, rv + 0 * WC, ZB(2));
  k_mid<<<ZGRID, 512, 0, stream>>>(lk, lr, lb, ZB(2), cA, cB, rv + 1 * WC, ZB(3));
  k_mid<<<ZGRID, 512, 0, stream>>>(lk, lr, lb, ZB(3), cB, cA, rv + 2 * WC, ZB(4));
  k_mid<<<ZGRID, 512, 0, stream>>>(lk, lr, lb, ZB(4), cA, cB, rv + 3 * WC, ZB(5));
  k_last<<<PGRID, 512, 0, stream>>>(lb, ZB(5), cB, Wo, Wi, ws);
  k_scores<<<512, 512, 0, stream>>>(M, us, out, ws);
  k_tail<<<512, 512, 0, stream>>>(out, ws);
}